// Round 6
// baseline (389.640 us; speedup 1.0000x reference)
//
#include <hip/hip_runtime.h>

// One-pole IIR: out_t = b0*x_t + s_t ; s_{t+1} = a1c*s_t + k1*x_t,
// k1 = b1 + a1c*b0. |a1c| <= 0.5 -> 32-step halo truncation (~2^-32).
//
// v6b (v6 with compile fix: __builtin_nontemporal_store needs a native
// clang ext_vector type, not HIP_vector_type<float,4>).
// Established so far: dur == hbm_bytes / (2.45..2.84 TB/s) in ALL
// versions; pipeline depth moved BW (+16%, v5), access-order locality
// moved traffic (v5 grid-stride scatter: +86 MB churn); FETCH pinned at
// 66 MB ~= half the input because the 268 MB working set marginally
// exceeds the 256 MB LLC -- output allocation evicts input.
// Changes vs v4:
//  - NON-TEMPORAL stores: output is write-once/never-read; nt keeps it
//    from evicting input in the LLC -> input fully resident -> FETCH -> ~0.
//  - Keep v5's depth-2 pipeline but with DENSE mapping: each wave owns
//    2048 consecutive floats (2 tiles); all loads issued up front; 4096
//    blocks in dispatch order keep a dense rolling frontier.
//  - Tile 1's halo is free: entering state = W0[63] + a^16*W0[62] from
//    tile 0's in-register window sums (2 shuffles, no halo load).
// Math per tile unchanged from v4: per-lane window sum W over 16 floats,
// s_in(lane) = W_{l-1} + a^16 W_{l-2}; lanes 0/1 of tile 0 get halo
// windows from an 8-lane cooperative load + 4-lane shfl reduce.

#define BLOCK 256
#define PER_LANE 16                       // floats per lane per tile (one 64B line)
#define PER_WAVE 1024                     // floats per wave per tile
#define TILES 2
#define WAVE_TOTAL (PER_WAVE * TILES)     // 2048 consecutive floats per wave
#define PER_BLOCK (4 * WAVE_TOTAL)        // 8192
#define T_LEN 131072                      // WAVE_TOTAL | T_LEN: no row straddle

typedef float nfloat4 __attribute__((ext_vector_type(4)));  // native vec for nt store

__global__ __launch_bounds__(BLOCK, 8) void onepole_kernel(
    const float* __restrict__ x,
    const float* __restrict__ b0p,
    const float* __restrict__ b1p,
    const float* __restrict__ a1p,
    float* __restrict__ out)
{
    const int tid  = threadIdx.x;
    const int lane = tid & 63;
    const int wid  = tid >> 6;

    const float b0 = b0p[0];
    const float b1 = b1p[0];
    float a = a1p[0];
    a = fminf(1.0f, fmaxf(-1.0f, a));
    const float k1  = fmaf(a, b0, b1);
    const float a2  = a * a;
    const float a3  = a2 * a;
    const float a4  = a2 * a2;
    const float a8  = a4 * a4;
    const float a12 = a8 * a4;
    const float a16 = a8 * a8;
    const float c0 = k1, c1 = k1 * a, c2 = k1 * a2, c3 = k1 * a3;

    const long long wbase = (long long)blockIdx.x * PER_BLOCK
                          + (long long)wid * WAVE_TOTAL;
    const long long wq    = wbase >> 2;            // float4 index of wave base
    const long long q0    = wq + lane * 4;         // tile0: lane's 64B line
    const long long q1    = q0 + (PER_WAVE >> 2);  // tile1: +256 quads

    const float4* xq = (const float4*)x;
    nfloat4* oq = (nfloat4*)out;

    // ---- issue ALL loads up front (9 instructions, no deps) ----
    float4 v0 = xq[q0 + 0];
    float4 v1 = xq[q0 + 1];
    float4 v2 = xq[q0 + 2];
    float4 v3 = xq[q0 + 3];
    float4 u0 = xq[q1 + 0];
    float4 u1 = xq[q1 + 1];
    float4 u2 = xq[q1 + 2];
    float4 u3 = xq[q1 + 3];
    float4 h  = make_float4(0.f, 0.f, 0.f, 0.f);
    const bool rowstart = ((wbase & (long long)(T_LEN - 1)) == 0);
    if (lane < 8 && !rowstart)
        h = xq[wq - 8 + lane];                     // 32 floats before wave base

    // ---- tile 0: window partials and full-window sum ----
    const float pq0 = fmaf(c3, v0.x, fmaf(c2, v0.y, fmaf(c1, v0.z, c0 * v0.w)));
    const float pq1 = fmaf(c3, v1.x, fmaf(c2, v1.y, fmaf(c1, v1.z, c0 * v1.w)));
    const float pq2 = fmaf(c3, v2.x, fmaf(c2, v2.y, fmaf(c1, v2.z, c0 * v2.w)));
    const float pq3 = fmaf(c3, v3.x, fmaf(c2, v3.y, fmaf(c1, v3.z, c0 * v3.w)));
    const float W0  = fmaf(a4, fmaf(a4, fmaf(a4, pq0, pq1), pq2), pq3);

    // halo windows Wm1 ([-16,0)) / Wm2 ([-32,-16)) for tile 0 lanes 0/1
    const float ph = fmaf(c3, h.x, fmaf(c2, h.y, fmaf(c1, h.z, c0 * h.w)));
    const int   r  = lane & 3;
    const float wsc = (r == 0) ? a12 : (r == 1) ? a8 : (r == 2) ? a4 : 1.0f;
    float phs = ph * wsc;                 // garbage on lanes >= 8 (never read)
    phs += __shfl_xor(phs, 1, 64);
    phs += __shfl_xor(phs, 2, 64);        // lanes 0-3 -> Wm2, lanes 4-7 -> Wm1
    const float Wm2 = __shfl(phs, 0, 64);
    const float Wm1 = __shfl(phs, 4, 64);

    const float s1u = __shfl_up(W0, 1, 64);
    const float s2u = __shfl_up(W0, 2, 64);
    const float A0  = (lane >= 1) ? s1u : Wm1;
    const float B0  = (lane >= 2) ? s2u : ((lane == 1) ? Wm1 : Wm2);
    float s = fmaf(a16, B0, A0);          // entering state, tile 0

#define QUAD(V, PQ, DSTQ)                                                   \
    {                                                                       \
        const float4 v = (V);                                               \
        const float t1 = fmaf(c0, v.x, b0 * v.y);                           \
        const float t2 = fmaf(c1, v.x, fmaf(c0, v.y, b0 * v.z));            \
        const float t3 = fmaf(c2, v.x, fmaf(c1, v.y, fmaf(c0, v.z, b0 * v.w))); \
        nfloat4 o;                                                          \
        o.x = fmaf(b0, v.x, s);                                             \
        o.y = fmaf(a,  s, t1);                                              \
        o.z = fmaf(a2, s, t2);                                              \
        o.w = fmaf(a3, s, t3);                                              \
        s = fmaf(a4, s, (PQ));                                              \
        __builtin_nontemporal_store(o, &oq[(DSTQ)]);                        \
    }

    QUAD(v0, pq0, q0 + 0)
    QUAD(v1, pq1, q0 + 1)
    QUAD(v2, pq2, q0 + 2)
    QUAD(v3, pq3, q0 + 3)

    // ---- tile 1: halo comes from tile 0's in-register window sums ----
    const float rq0 = fmaf(c3, u0.x, fmaf(c2, u0.y, fmaf(c1, u0.z, c0 * u0.w)));
    const float rq1 = fmaf(c3, u1.x, fmaf(c2, u1.y, fmaf(c1, u1.z, c0 * u1.w)));
    const float rq2 = fmaf(c3, u2.x, fmaf(c2, u2.y, fmaf(c1, u2.z, c0 * u2.w)));
    const float rq3 = fmaf(c3, u3.x, fmaf(c2, u3.y, fmaf(c1, u3.z, c0 * u3.w)));
    const float W1  = fmaf(a4, fmaf(a4, fmaf(a4, rq0, rq1), rq2), rq3);

    const float Wp1 = __shfl(W0, 63, 64); // window [-16,0) of tile 1
    const float Wp2 = __shfl(W0, 62, 64); // window [-32,-16)
    const float t1u = __shfl_up(W1, 1, 64);
    const float t2u = __shfl_up(W1, 2, 64);
    const float A1  = (lane >= 1) ? t1u : Wp1;
    const float B1  = (lane >= 2) ? t2u : ((lane == 1) ? Wp1 : Wp2);
    s = fmaf(a16, B1, A1);                // entering state, tile 1

    QUAD(u0, rq0, q1 + 0)
    QUAD(u1, rq1, q1 + 1)
    QUAD(u2, rq2, q1 + 2)
    QUAD(u3, rq3, q1 + 3)
#undef QUAD
}

extern "C" void kernel_launch(void* const* d_in, const int* in_sizes, int n_in,
                              void* d_out, int out_size, void* d_ws, size_t ws_size,
                              hipStream_t stream) {
    const float* x   = (const float*)d_in[0];
    const float* b0p = (const float*)d_in[1];
    const float* b1p = (const float*)d_in[2];
    const float* a1p = (const float*)d_in[3];
    float* outp = (float*)d_out;

    const int total  = in_sizes[0];            // B * T = 33554432 elements
    const int blocks = total / PER_BLOCK;      // 4096

    onepole_kernel<<<blocks, BLOCK, 0, stream>>>(x, b0p, b1p, a1p, outp);
}

// Round 7
// 235.744 us; speedup vs baseline: 1.6528x; 1.6528x over previous
//
#include <hip/hip_runtime.h>

// One-pole IIR: out_t = b0*x_t + s_t ; s_{t+1} = a1c*s_t + k1*x_t,
// k1 = b1 + a1c*b0. |a1c| <= 0.5 -> 32-step truncation (~2^-32), as all
// prior passing versions.
//
// v7: DENSE lane-interleaved layout (the copy-ubench request shape).
// Evidence: v4/v5/v6 (lane-contiguous, 64B/lane) all pinned at 2.45-2.84
// TB/s; their loads touch 64 lines/instr for 1KB useful (4x line-request
// rate) and stores write 64 quarter-lines/instr (nt-store experiment
// proved quarter-line writes are real: WRITE 131->377MB when L2 merge was
// bypassed). Dense layout: load/store instruction i handles quad
// (i*64+lane) -> 16 full lines per instruction on BOTH streams.
//
// Math: quad-granular truncated scan. Per quad p = c3*x0+c2*x1+c1*x2+c0*x3
// (state contribution); running state sigma_j = a4*sigma_{j-1} + p_j.
// Within a 64-quad group: 3-step masked shfl_up scan (ratios a4,a8,a16)
// gives 8-quad-window sums G; carry C from previous group adds with
// per-lane weight cw_l = a^{4(l+1)} (underflows ~l>=16). Group carry
// C_out = G[lane 63] (a^256 == 0 -> carries INDEPENDENT, no serial chain;
// all 8 groups of the wave's 2048 floats scan in parallel).
// Entering state of quad l: S_l = R_{l-1} (shfl_up), lane 0 <- C_in.
// Wave halo (32 floats before wave base): 8-lane cooperative load +
// weighted 8-lane shfl_xor reduce -> sigma entering the wave.
// Stores: plain float4 (L2 write-combine; nt REFUTED in v6b).

#define BLOCK 256
#define PER_WAVE 1024                     // floats per wave per tile
#define WAVE_TOTAL 2048                   // 2 tiles, consecutive
#define PER_BLOCK (4 * WAVE_TOTAL)        // 8192
#define T_LEN 131072                      // WAVE_TOTAL | T_LEN: no row straddle

__global__ __launch_bounds__(BLOCK, 8) void onepole_kernel(
    const float* __restrict__ x,
    const float* __restrict__ b0p,
    const float* __restrict__ b1p,
    const float* __restrict__ a1p,
    float* __restrict__ out)
{
    const int tid  = threadIdx.x;
    const int lane = tid & 63;
    const int wid  = tid >> 6;

    const float b0 = b0p[0];
    const float b1 = b1p[0];
    float a = a1p[0];
    a = fminf(1.0f, fmaxf(-1.0f, a));
    const float k1  = fmaf(a, b0, b1);
    const float a2  = a * a;
    const float a3  = a2 * a;
    const float a4  = a2 * a2;           // scan ratio
    const float a8  = a4 * a4;
    const float a16 = a8 * a8;
    const float w32  = a16 * a16;        // a^32
    const float w64  = w32 * w32;
    const float w128 = w64 * w64;
    const float w256 = w128 * w128;      // == 0.f at |a|<=0.5
    const float c0 = k1, c1 = k1 * a, c2 = k1 * a2, c3 = k1 * a3;

    // per-lane carry weight cw = a^{4*(lane+1)}  (binary exponentiation)
    {} // (scoped below to keep names tight)
    const int e = lane + 1;              // 1..64
    float cw = 1.0f;
    if (e & 1)  cw *= a4;
    if (e & 2)  cw *= a8;
    if (e & 4)  cw *= a16;
    if (e & 8)  cw *= w32;
    if (e & 16) cw *= w64;
    if (e & 32) cw *= w128;
    if (e & 64) cw *= w256;
    // per-lane halo weight hw = a^{4*(7-lane)} (only lanes 0-7 used)
    const int m = (7 - lane) & 7;
    float hw = 1.0f;
    if (m & 1) hw *= a4;
    if (m & 2) hw *= a8;
    if (m & 4) hw *= a16;

    const long long wbase = (long long)blockIdx.x * PER_BLOCK
                          + (long long)wid * WAVE_TOTAL;
    const long long wq    = wbase >> 2;          // float4 index of wave base

    const float4* xq = (const float4*)x;
    float4* oq = (float4*)out;

    // ---- issue ALL loads up front, dense: instr i -> quad i*64+lane ----
    float4 A0 = xq[wq +   0 + lane];
    float4 A1 = xq[wq +  64 + lane];
    float4 A2 = xq[wq + 128 + lane];
    float4 A3 = xq[wq + 192 + lane];
    float4 B0 = xq[wq + 256 + lane];
    float4 B1 = xq[wq + 320 + lane];
    float4 B2 = xq[wq + 384 + lane];
    float4 B3 = xq[wq + 448 + lane];
    float4 h  = make_float4(0.f, 0.f, 0.f, 0.f);
    const bool rowstart = ((wbase & (long long)(T_LEN - 1)) == 0);
    if (lane < 8 && !rowstart)
        h = xq[wq - 8 + lane];                   // 32 floats before wave base

#define PSUM(V) fmaf(c3, (V).x, fmaf(c2, (V).y, fmaf(c1, (V).z, c0 * (V).w)))

    const float pA0 = PSUM(A0), pA1 = PSUM(A1), pA2 = PSUM(A2), pA3 = PSUM(A3);
    const float pB0 = PSUM(B0), pB1 = PSUM(B1), pB2 = PSUM(B2), pB3 = PSUM(B3);

    // ---- halo: sigma entering the wave (zero at row start) ----
    const float ph = PSUM(h);                    // 0 on lanes >= 8 (h == 0)
    float hs = ph * hw;
    hs += __shfl_xor(hs, 1, 64);
    hs += __shfl_xor(hs, 2, 64);
    hs += __shfl_xor(hs, 4, 64);
    const float Chalo = __shfl(hs, 0, 64);

    // ---- per-group scan: G (8-quad window), Cout = G[63] (a^256 == 0) ----
#define SCAN(P, CIN, S_, COUT_)                                             \
    {                                                                       \
        float G = (P), t_;                                                  \
        t_ = __shfl_up(G, 1, 64); G = fmaf(a4,  (lane >= 1) ? t_ : 0.f, G); \
        t_ = __shfl_up(G, 2, 64); G = fmaf(a8,  (lane >= 2) ? t_ : 0.f, G); \
        t_ = __shfl_up(G, 4, 64); G = fmaf(a16, (lane >= 4) ? t_ : 0.f, G); \
        COUT_ = __shfl(G, 63, 64);                                          \
        const float R  = fmaf(cw, (CIN), G);                                \
        const float Sp = __shfl_up(R, 1, 64);                               \
        S_ = (lane == 0) ? (CIN) : Sp;                                      \
    }

    float S0, S1, S2, S3, S4, S5, S6, S7;
    float C0, C1, C2, C3, C4, C5, C6, C7;
    SCAN(pA0, Chalo, S0, C0)
    SCAN(pA1, C0,    S1, C1)
    SCAN(pA2, C1,    S2, C2)
    SCAN(pA3, C2,    S3, C3)
    SCAN(pB0, C3,    S4, C4)
    SCAN(pB1, C4,    S5, C5)
    SCAN(pB2, C5,    S6, C6)
    SCAN(pB3, C6,    S7, C7)
    (void)C7;
#undef SCAN

    // ---- outputs: quad entering state S; dense full-line stores ----
#define OUTQ(V, S, QIDX)                                                    \
    {                                                                       \
        const float4 v = (V);                                               \
        const float s  = (S);                                               \
        const float t1 = fmaf(c0, v.x, b0 * v.y);                           \
        const float t2 = fmaf(c1, v.x, fmaf(c0, v.y, b0 * v.z));            \
        const float t3 = fmaf(c2, v.x, fmaf(c1, v.y, fmaf(c0, v.z, b0 * v.w))); \
        float4 o;                                                           \
        o.x = fmaf(b0, v.x, s);                                             \
        o.y = fmaf(a,  s, t1);                                              \
        o.z = fmaf(a2, s, t2);                                              \
        o.w = fmaf(a3, s, t3);                                              \
        oq[(QIDX)] = o;                                                     \
    }

    OUTQ(A0, S0, wq +   0 + lane)
    OUTQ(A1, S1, wq +  64 + lane)
    OUTQ(A2, S2, wq + 128 + lane)
    OUTQ(A3, S3, wq + 192 + lane)
    OUTQ(B0, S4, wq + 256 + lane)
    OUTQ(B1, S5, wq + 320 + lane)
    OUTQ(B2, S6, wq + 384 + lane)
    OUTQ(B3, S7, wq + 448 + lane)
#undef OUTQ
#undef PSUM
}

extern "C" void kernel_launch(void* const* d_in, const int* in_sizes, int n_in,
                              void* d_out, int out_size, void* d_ws, size_t ws_size,
                              hipStream_t stream) {
    const float* x   = (const float*)d_in[0];
    const float* b0p = (const float*)d_in[1];
    const float* b1p = (const float*)d_in[2];
    const float* a1p = (const float*)d_in[3];
    float* outp = (float*)d_out;

    const int total  = in_sizes[0];            // B * T = 33554432 elements
    const int blocks = total / PER_BLOCK;      // 4096

    onepole_kernel<<<blocks, BLOCK, 0, stream>>>(x, b0p, b1p, a1p, outp);
}